// Round 5
// baseline (261.034 us; speedup 1.0000x reference)
//
#include <hip/hip_runtime.h>
#include <hip/hip_bf16.h>
#include <math.h>

#define B_ 2
#define S_ 2048
#define E_ 1024
#define H_ 16
#define D_ 64
#define M_ 4096   // B_*S_
#define NT2 32    // D_/2
#define KVB 64

typedef __bf16 bf16;
typedef __bf16 bf16x4 __attribute__((ext_vector_type(4)));
typedef __bf16 bf16x8 __attribute__((ext_vector_type(8)));
typedef float f32x4 __attribute__((ext_vector_type(4)));
typedef float f32x16 __attribute__((ext_vector_type(16)));

__device__ __forceinline__ void gload_lds16(const void* g, void* lds) {
  __builtin_amdgcn_global_load_lds(
      (const __attribute__((address_space(1))) unsigned int*)g,
      (__attribute__((address_space(3))) unsigned int*)lds, 16, 0, 0);
}

#define MFMA16(a, b, c) __builtin_amdgcn_mfma_f32_16x16x32_bf16(a, b, c, 0, 0, 0)
#define MFMA32(a, b, c) __builtin_amdgcn_mfma_f32_32x32x16_bf16(a, b, c, 0, 0, 0)

// ---------------- split fp32 -> bf16 hi/lo ----------------
__global__ __launch_bounds__(256)
void split_f32_kernel(const float* __restrict__ in, bf16* __restrict__ hi,
                      bf16* __restrict__ lo, int n4) {
  int i = blockIdx.x * 256 + threadIdx.x;
  if (i >= n4) return;
  float4 v = ((const float4*)in)[i];
  bf16 h0 = (bf16)v.x, h1 = (bf16)v.y, h2 = (bf16)v.z, h3 = (bf16)v.w;
  bf16x4 hv = {h0, h1, h2, h3};
  bf16x4 lv = {(bf16)(v.x - (float)h0), (bf16)(v.y - (float)h1),
               (bf16)(v.z - (float)h2), (bf16)(v.w - (float)h3)};
  *(bf16x4*)(hi + 4 * (size_t)i) = hv;
  *(bf16x4*)(lo + 4 * (size_t)i) = lv;
}

// ---------------- transpose + split W [K][N] -> T[N][K] hi/lo ----------------
__global__ __launch_bounds__(256)
void transpose_split_kernel(const float* __restrict__ W, bf16* __restrict__ Th,
                            bf16* __restrict__ Tl) {
  __shared__ float tile[32][33];
  const int tx = threadIdx.x & 31, ty = threadIdx.x >> 5;  // ty 0..7
  const int c0 = blockIdx.x * 32, r0 = blockIdx.y * 32;
#pragma unroll
  for (int i = 0; i < 4; ++i)
    tile[ty + 8 * i][tx] = W[(size_t)(r0 + ty + 8 * i) * E_ + c0 + tx];
  __syncthreads();
#pragma unroll
  for (int i = 0; i < 4; ++i) {
    int rr = ty + 8 * i;
    float v = tile[tx][rr];  // = W[r0+tx][c0+rr]
    bf16 hv = (bf16)v;
    size_t oidx = (size_t)(c0 + rr) * E_ + r0 + tx;
    Th[oidx] = hv;
    Tl[oidx] = (bf16)(v - (float)hv);
  }
}

// ---------------- RoPE cos/sin table ----------------
__global__ __launch_bounds__(256)
void rope_tab_kernel(const int* __restrict__ pos, float* __restrict__ cosT,
                     float* __restrict__ sinT) {
  int idx = blockIdx.x * 256 + threadIdx.x;  // B_*S_*NT2
  int t = idx & 31, bs = idx >> 5;
  double th = pow(10000.0, -(double)(2 * t) / 64.0);
  float ang = (float)pos[bs] * (float)th;  // fp32 product (matches ref rounding)
  double a = (double)ang;
  cosT[idx] = (float)cos(a);
  sinT[idx] = (float)sin(a);
}

// ---------------- fused QKV split-bf16 GEMM ----------------
// LDS tiles [128][32]bf16, slot-swizzled (u ^= (row>>1)&3) via pre-swizzled
// global source; fragment reads XOR the same sigma.
// Double-buffered 2-phase pipeline: stage(t+1) issued BEFORE compute(t); the
// single end-of-iter __syncthreads (vmcnt(0)+barrier) catches stragglers, so
// staging latency hides under the 24-MFMA compute phase.
#define BMg 128
#define BNg 128
#define BKg 32

__global__ __launch_bounds__(256)
void gemm_qkv_kernel(const bf16* __restrict__ Ah_g, const bf16* __restrict__ Al_g,
                     const bf16* __restrict__ BhQ, const bf16* __restrict__ BlQ,
                     const bf16* __restrict__ BhK, const bf16* __restrict__ BlK,
                     const bf16* __restrict__ BhV, const bf16* __restrict__ BlV,
                     const float* __restrict__ bqp, const float* __restrict__ bkp,
                     const float* __restrict__ bvp,
                     const float* __restrict__ cosT, const float* __restrict__ sinT,
                     bf16* __restrict__ Qh, bf16* __restrict__ Qlo,
                     bf16* __restrict__ Kh, bf16* __restrict__ Klo,
                     bf16* __restrict__ VTb) {
  __shared__ bf16 lA_h[2][BMg * BKg], lA_l[2][BMg * BKg];
  __shared__ bf16 lB_h[2][BNg * BKg], lB_l[2][BNg * BKg];
  const int tid = threadIdx.x;
  const int nb = blockIdx.x;        // 0..23
  const int third = nb >> 3;        // 0=Q 1=K 2=V
  const int n0 = (nb & 7) * BNg;
  const int m0 = blockIdx.y * BMg;
  const bf16* Bh_g = third == 0 ? BhQ : third == 1 ? BhK : BhV;
  const bf16* Bl_g = third == 0 ? BlQ : third == 1 ? BlK : BlV;
  const float* bias = third == 0 ? bqp : third == 1 ? bkp : bvp;
  const int wave = tid >> 6, lane = tid & 63;
  const int wr = wave >> 1, wc = wave & 1;
  const int r = lane & 31, half = lane >> 5;
  const int KD = 1024;
  const int NK = KD / BKg;

  f32x16 acc[2][2] = {};

  auto stage = [&](int kt, int buf) {
    const int k0 = kt * BKg;
    const bf16* gsrc[4] = {Ah_g, Al_g, Bh_g, Bl_g};
    bf16* ldst[4] = {&lA_h[buf][0], &lA_l[buf][0], &lB_h[buf][0], &lB_l[buf][0]};
    const int rs[4] = {m0, m0, n0, n0};
#pragma unroll
    for (int mm = 0; mm < 4; ++mm) {
#pragma unroll
      for (int i = 0; i < 2; ++i) {
        int c = i * 256 + tid;
        int row = c >> 2, u = c & 3;
        int us = u ^ ((row >> 1) & 3);  // pre-swizzled source slot
        const char* gp =
            (const char*)(gsrc[mm] + (size_t)(rs[mm] + row) * KD + k0) + us * 16;
        char* lp = (char*)ldst[mm] + (size_t)(i * 256 + wave * 64) * 16;
        gload_lds16(gp, lp);
      }
    }
  };

  stage(0, 0);
  __syncthreads();
  int cur = 0;

  for (int kt = 0; kt < NK; ++kt) {
    if (kt + 1 < NK) stage(kt + 1, cur ^ 1);  // prefetch; hides under MFMAs
#pragma unroll
    for (int ks = 0; ks < 2; ++ks) {
      bf16x8 a_h[2], a_l[2], b_h[2], b_l[2];
#pragma unroll
      for (int mi = 0; mi < 2; ++mi) {
        int row = wr * 64 + mi * 32 + r;
        int boff = row * 64 + ((ks * 32 + half * 16) ^ (((row >> 1) & 3) << 4));
        a_h[mi] = *(const bf16x8*)((const char*)&lA_h[cur][0] + boff);
        a_l[mi] = *(const bf16x8*)((const char*)&lA_l[cur][0] + boff);
      }
#pragma unroll
      for (int ni = 0; ni < 2; ++ni) {
        int row = wc * 64 + ni * 32 + r;
        int boff = row * 64 + ((ks * 32 + half * 16) ^ (((row >> 1) & 3) << 4));
        b_h[ni] = *(const bf16x8*)((const char*)&lB_h[cur][0] + boff);
        b_l[ni] = *(const bf16x8*)((const char*)&lB_l[cur][0] + boff);
      }
#pragma unroll
      for (int mi = 0; mi < 2; ++mi)
#pragma unroll
        for (int ni = 0; ni < 2; ++ni) {
          acc[mi][ni] = MFMA32(a_h[mi], b_h[ni], acc[mi][ni]);
          acc[mi][ni] = MFMA32(a_h[mi], b_l[ni], acc[mi][ni]);
          acc[mi][ni] = MFMA32(a_l[mi], b_h[ni], acc[mi][ni]);
        }
    }
    __syncthreads();  // drains vmcnt: tile kt+1 ready; buf[cur] free to reuse
    cur ^= 1;
  }

  // ---- epilogue ----
#pragma unroll
  for (int mi = 0; mi < 2; ++mi)
#pragma unroll
    for (int ni = 0; ni < 2; ++ni) {
      const int gcol = n0 + wc * 64 + ni * 32 + r;
      const float bv = bias[gcol];
      if (third < 2) {  // Q or K: RoPE (+scale for Q), split
        bf16* outH = third == 0 ? Qh : Kh;
        bf16* outL = third == 0 ? Qlo : Klo;
        const int h = gcol >> 6, d = gcol & 63, tt = d >> 1;
#pragma unroll
        for (int tq = 0; tq < 4; ++tq) {
#pragma unroll
          for (int u = 0; u < 4; ++u) {
            int reg = tq * 4 + u;
            int grow = m0 + wr * 64 + mi * 32 + (u + 8 * tq + 4 * half);
            int s = grow & (S_ - 1), b = grow >> 11;
            float v = acc[mi][ni][reg] + bv;
            float other = __shfl_xor(v, 1);  // partner dim (d^1)
            float cs = cosT[(size_t)(b * S_ + s) * NT2 + tt];
            float sn = sinT[(size_t)(b * S_ + s) * NT2 + tt];
            float vr = (d & 1) ? (other * sn + v * cs) : (v * cs - other * sn);
            if (third == 0) vr *= 0.125f;  // 1/sqrt(D)
            bf16 hv = (bf16)vr;
            bf16 lv = (bf16)(vr - (float)hv);
            size_t idx = (((size_t)(b * H_ + h)) * S_ + s) * D_ + d;
            outH[idx] = hv;
            outL[idx] = lv;
          }
        }
      } else {  // V: bf16, transposed [B,H,D,S]
        const int h = gcol >> 6, d = gcol & 63;
#pragma unroll
        for (int tq = 0; tq < 4; ++tq) {
          int grow = m0 + wr * 64 + mi * 32 + (8 * tq + 4 * half);
          int s = grow & (S_ - 1), b = grow >> 11;
          ushort4 pk;
          unsigned short* pp = (unsigned short*)&pk;
#pragma unroll
          for (int u = 0; u < 4; ++u) {
            float v = acc[mi][ni][tq * 4 + u] + bv;
            bf16 hv = (bf16)v;
            pp[u] = __builtin_bit_cast(unsigned short, hv);
          }
          *(ushort4*)((unsigned short*)VTb +
                      (((size_t)(b * H_ + h)) * D_ + d) * S_ + s) = pk;
        }
      }
    }
}

// ---------------- O-projection split-bf16 GEMM ----------------
__global__ __launch_bounds__(256)
void gemm_o_kernel(const bf16* __restrict__ Ah_g, const bf16* __restrict__ Al_g,
                   const bf16* __restrict__ Bh_g, const bf16* __restrict__ Bl_g,
                   const float* __restrict__ bias, float* __restrict__ outF) {
  __shared__ bf16 lA_h[2][BMg * BKg], lA_l[2][BMg * BKg];
  __shared__ bf16 lB_h[2][BNg * BKg], lB_l[2][BNg * BKg];
  const int tid = threadIdx.x;
  const int m0 = blockIdx.y * BMg, n0 = blockIdx.x * BNg;
  const int wave = tid >> 6, lane = tid & 63;
  const int wr = wave >> 1, wc = wave & 1;
  const int r = lane & 31, half = lane >> 5;
  const int KD = 1024;
  const int NK = KD / BKg;

  f32x16 acc[2][2] = {};

  auto stage = [&](int kt, int buf) {
    const int k0 = kt * BKg;
    const bf16* gsrc[4] = {Ah_g, Al_g, Bh_g, Bl_g};
    bf16* ldst[4] = {&lA_h[buf][0], &lA_l[buf][0], &lB_h[buf][0], &lB_l[buf][0]};
    const int rs[4] = {m0, m0, n0, n0};
#pragma unroll
    for (int mm = 0; mm < 4; ++mm) {
#pragma unroll
      for (int i = 0; i < 2; ++i) {
        int c = i * 256 + tid;
        int row = c >> 2, u = c & 3;
        int us = u ^ ((row >> 1) & 3);
        const char* gp =
            (const char*)(gsrc[mm] + (size_t)(rs[mm] + row) * KD + k0) + us * 16;
        char* lp = (char*)ldst[mm] + (size_t)(i * 256 + wave * 64) * 16;
        gload_lds16(gp, lp);
      }
    }
  };

  stage(0, 0);
  __syncthreads();
  int cur = 0;

  for (int kt = 0; kt < NK; ++kt) {
    if (kt + 1 < NK) stage(kt + 1, cur ^ 1);
#pragma unroll
    for (int ks = 0; ks < 2; ++ks) {
      bf16x8 a_h[2], a_l[2], b_h[2], b_l[2];
#pragma unroll
      for (int mi = 0; mi < 2; ++mi) {
        int row = wr * 64 + mi * 32 + r;
        int boff = row * 64 + ((ks * 32 + half * 16) ^ (((row >> 1) & 3) << 4));
        a_h[mi] = *(const bf16x8*)((const char*)&lA_h[cur][0] + boff);
        a_l[mi] = *(const bf16x8*)((const char*)&lA_l[cur][0] + boff);
      }
#pragma unroll
      for (int ni = 0; ni < 2; ++ni) {
        int row = wc * 64 + ni * 32 + r;
        int boff = row * 64 + ((ks * 32 + half * 16) ^ (((row >> 1) & 3) << 4));
        b_h[ni] = *(const bf16x8*)((const char*)&lB_h[cur][0] + boff);
        b_l[ni] = *(const bf16x8*)((const char*)&lB_l[cur][0] + boff);
      }
#pragma unroll
      for (int mi = 0; mi < 2; ++mi)
#pragma unroll
        for (int ni = 0; ni < 2; ++ni) {
          acc[mi][ni] = MFMA32(a_h[mi], b_h[ni], acc[mi][ni]);
          acc[mi][ni] = MFMA32(a_h[mi], b_l[ni], acc[mi][ni]);
          acc[mi][ni] = MFMA32(a_l[mi], b_h[ni], acc[mi][ni]);
        }
    }
    __syncthreads();
    cur ^= 1;
  }

#pragma unroll
  for (int mi = 0; mi < 2; ++mi)
#pragma unroll
    for (int ni = 0; ni < 2; ++ni) {
      const int gcol = n0 + wc * 64 + ni * 32 + r;
      const float bv = bias[gcol];
#pragma unroll
      for (int tq = 0; tq < 4; ++tq)
#pragma unroll
        for (int u = 0; u < 4; ++u) {
          int grow = m0 + wr * 64 + mi * 32 + (u + 8 * tq + 4 * half);
          outF[(size_t)grow * E_ + gcol] = acc[mi][ni][tq * 4 + u] + bv;
        }
    }
}

// ---------------- flash attention (in-register softmax, swapped QK^T) -------
// Q,K: [B,H,S,D] bf16 hi/lo (Q pre-scaled by 1/8).  VT: [B,H,D,S] bf16.
// Out: ctx split hi/lo, layout [B,S,H,D].
// Swapped QK^T: S[key][q] -> each lane holds 16 scores for ONE q (=lane&15).
// Defer-max (THR=8): fast path has zero cross-lane ops; l kept per-lane.
// P stays in registers (scalar bf16 casts -> PV A-frags).
// V LDS columns stored in pa's key order sigma: p(y) = (y>>5)*32 +
//   (((y&15)>>2))*8 + ((y>>4)&1)*4 + (y&3); register-staged (T14 split).
__global__ __launch_bounds__(256)
void attn_kernel(const bf16* __restrict__ Qh, const bf16* __restrict__ Ql,
                 const bf16* __restrict__ Kh, const bf16* __restrict__ Kl,
                 const bf16* __restrict__ VT, bf16* __restrict__ Ch,
                 bf16* __restrict__ Cl) {
  __shared__ bf16 sKh[2][KVB * 64];
  __shared__ bf16 sKl[2][KVB * 64];
  __shared__ bf16 sV[2][KVB * 64];  // [d=64][key-pos=64], row-XOR-swizzled

  const int tid = threadIdx.x;
  const int wave = tid >> 6, lane = tid & 63;
  const int r = lane & 15, hq = lane >> 4;
  const int bid = blockIdx.x;
  const int swz = (bid & 7) * 64 + (bid >> 3);  // XCD-chunked (512 % 8 == 0)
  const int bh = swz >> 4, qblk = swz & 15;
  const int q0 = qblk * 128 + wave * 32;
  const size_t hb = (size_t)bh * (S_ * D_);
  const size_t vb = (size_t)bh * (D_ * S_);

  // Q fragments in registers (B-operand of swapped QK^T; layout unchanged)
  bf16x8 qh[2][2], ql[2][2];
#pragma unroll
  for (int mi = 0; mi < 2; ++mi)
#pragma unroll
    for (int ks = 0; ks < 2; ++ks) {
      size_t off = hb + (size_t)(q0 + mi * 16 + r) * D_ + ks * 32 + hq * 8;
      qh[mi][ks] = *(const bf16x8*)&Qh[off];
      ql[mi][ks] = *(const bf16x8*)&Ql[off];
    }

  float m_lane[2] = {-1e30f, -1e30f};  // running max for q = r, per mi
  float l_lane[2] = {0.f, 0.f};        // per-lane partial denominator
  f32x4 o[2][4] = {};

  // K staging: global_load_lds, XOR-swizzled via pre-swizzled source chunks
  auto stageK = [&](int kt, int buf) {
    const bf16* kbh = Kh + hb + (size_t)kt * (KVB * D_);
    const bf16* kbl = Kl + hb + (size_t)kt * (KVB * D_);
#pragma unroll
    for (int i = 0; i < 2; ++i) {
      int c = i * 256 + tid;
      int ldo = (i * 256 + wave * 64) * 16;
      int cs = c ^ ((c >> 3) & 7);
      gload_lds16(kbh + cs * 8, (char*)&sKh[buf][0] + ldo);
      gload_lds16(kbl + cs * 8, (char*)&sKl[buf][0] + ldo);
    }
  };
  // V staging part 1: issue global loads into registers
  uint4 vld[2];
  auto loadV = [&](int kt) {
    const bf16* vbp = VT + vb + kt * KVB;
#pragma unroll
    for (int i = 0; i < 2; ++i) {
      int c = i * 256 + tid;
      int row = c >> 3, w = c & 7;  // row = d, w = key-chunk
      vld[i] = *(const uint4*)(vbp + (size_t)row * S_ + w * 8);
    }
  };
  // V staging part 2: ds_write in permuted-column order + row-XOR swizzle
  auto writeV = [&](int buf) {
#pragma unroll
    for (int i = 0; i < 2; ++i) {
      int c = i * 256 + tid;
      int row = c >> 3, w = c & 7;
      int pb0 = (w >> 2) * 32 + (w & 1) * 16 + ((w >> 1) & 1) * 4;  // elems
      char* base = (char*)&sV[buf][0] + row * 128;
      uint2 lo = {vld[i].x, vld[i].y};  // keys w*8+0..3 -> pos pb0..pb0+3
      uint2 hi = {vld[i].z, vld[i].w};  // keys w*8+4..7 -> pos pb0+8..pb0+11
      *(uint2*)(base + ((pb0 * 2) ^ ((row & 7) << 4))) = lo;
      *(uint2*)(base + (((pb0 + 8) * 2) ^ ((row & 7) << 4))) = hi;
    }
  };

  stageK(0, 0);
  loadV(0);
  writeV(0);
  __syncthreads();
  int cur = 0;

  for (int kt = 0; kt < S_ / KVB; ++kt) {
    if (kt + 1 < S_ / KVB) {
      stageK(kt + 1, cur ^ 1);
      loadV(kt + 1);  // issue early; write after PV (latency hidden)
    }

    // ---- QK^T (swapped: A=K, B=Q) -> sf[mi][nf][j]: key nf*16+hq*4+j, q=r
    f32x4 sf[2][4] = {};
#pragma unroll
    for (int nf = 0; nf < 4; ++nf)
#pragma unroll
      for (int ks = 0; ks < 2; ++ks) {
        int kk = nf * 16 + r;
        int boff = (kk * 128 + ks * 64 + hq * 16) ^ ((kk & 7) << 4);
        bf16x8 kkh = *(const bf16x8*)((const char*)&sKh[cur][0] + boff);
        bf16x8 kkl = *(const bf16x8*)((const char*)&sKl[cur][0] + boff);
#pragma unroll
        for (int mi = 0; mi < 2; ++mi) {
          sf[mi][nf] = MFMA16(kkh, qh[mi][ks], sf[mi][nf]);
          sf[mi][nf] = MFMA16(kkh, ql[mi][ks], sf[mi][nf]);
          sf[mi][nf] = MFMA16(kkl, qh[mi][ks], sf[mi][nf]);
        }
      }

    // ---- defer-max online softmax (lane-local fast path) ----
    float lmax[2];
#pragma unroll
    for (int mi = 0; mi < 2; ++mi) {
      f32x4 m4;
#pragma unroll
      for (int e = 0; e < 4; ++e)
        m4[e] = fmaxf(fmaxf(sf[mi][0][e], sf[mi][1][e]),
                      fmaxf(sf[mi][2][e], sf[mi][3][e]));
      lmax[mi] = fmaxf(fmaxf(m4[0], m4[1]), fmaxf(m4[2], m4[3]));
    }
    int need = (lmax[0] > m_lane[0] + 8.f) || (lmax[1] > m_lane[1] + 8.f);
    if (__any(need)) {  // slow path: recompute full max, rescale o & l
#pragma unroll
      for (int mi = 0; mi < 2; ++mi) {
        float mx = lmax[mi];
        mx = fmaxf(mx, __shfl_xor(mx, 16));
        mx = fmaxf(mx, __shfl_xor(mx, 32));
        float mn = fmaxf(m_lane[mi], mx);
        float al = __expf(m_lane[mi] - mn);
        l_lane[mi] *= al;
        m_lane[mi] = mn;
        int alb = __builtin_bit_cast(int, al);
#pragma unroll
        for (int j = 0; j < 4; ++j) {
          int g = __builtin_amdgcn_ds_bpermute((hq * 4 + j) * 4, alb);
          float a = __builtin_bit_cast(float, g);
#pragma unroll
          for (int nd = 0; nd < 4; ++nd) o[mi][nd][j] *= a;
        }
      }
    }
    // exp + per-lane partial l + pa fragments (P in registers)
    bf16x8 pa[2][2];
#pragma unroll
    for (int mi = 0; mi < 2; ++mi) {
      f32x4 s4 = {};
#pragma unroll
      for (int nf = 0; nf < 4; ++nf)
#pragma unroll
        for (int e = 0; e < 4; ++e) {
          float pv = __expf(sf[mi][nf][e] - m_lane[mi]);
          sf[mi][nf][e] = pv;
          s4[e] += pv;
        }
      l_lane[mi] += s4[0] + s4[1] + s4[2] + s4[3];
#pragma unroll
      for (int ks = 0; ks < 2; ++ks) {
        bf16x8 t;
#pragma unroll
        for (int e = 0; e < 4; ++e) {
          t[e] = (bf16)sf[mi][2 * ks][e];
          t[4 + e] = (bf16)sf[mi][2 * ks + 1][e];
        }
        pa[mi][ks] = t;
      }
    }

    // ---- PV: B-frags from sV (permuted cols match pa key order) ----
#pragma unroll
    for (int nd = 0; nd < 4; ++nd)
#pragma unroll
      for (int ks = 0; ks < 2; ++ks) {
        int dd = nd * 16 + r;
        int boff = (dd * 128 + ks * 64 + hq * 16) ^ ((dd & 7) << 4);
        bf16x8 vv = *(const bf16x8*)((const char*)&sV[cur][0] + boff);
#pragma unroll
        for (int mi = 0; mi < 2; ++mi)
          o[mi][nd] = MFMA16(pa[mi][ks], vv, o[mi][nd]);
      }

    if (kt + 1 < S_ / KVB) writeV(cur ^ 1);  // sV[cur^1] unread this iter
    __syncthreads();  // drains vmcnt(0)/lgkmcnt(0): next tile ready
    cur ^= 1;
  }

  // ---- epilogue: reduce l, broadcast to o-lanes, normalize, split, store ---
  const int b = bh >> 4, h = bh & 15;
  float lq[2][4];
#pragma unroll
  for (int mi = 0; mi < 2; ++mi) {
    float lr = l_lane[mi];
    lr += __shfl_xor(lr, 16);
    lr += __shfl_xor(lr, 32);
    int lb = __builtin_bit_cast(int, lr);
#pragma unroll
    for (int j = 0; j < 4; ++j) {
      int g = __builtin_amdgcn_ds_bpermute((hq * 4 + j) * 4, lb);
      lq[mi][j] = __builtin_bit_cast(float, g);
    }
  }
#pragma unroll
  for (int mi = 0; mi < 2; ++mi)
#pragma unroll
    for (int nd = 0; nd < 4; ++nd)
#pragma unroll
      for (int j = 0; j < 4; ++j) {
        int s = q0 + mi * 16 + hq * 4 + j;
        int d = nd * 16 + r;
        float ov = o[mi][nd][j] / lq[mi][j];
        bf16 hv = (bf16)ov;
        bf16 lv = (bf16)(ov - (float)hv);
        size_t idx = (((size_t)(b * S_ + s)) * H_ + h) * D_ + d;
        Ch[idx] = hv;
        Cl[idx] = lv;
      }
}

// ---------------- host ----------------
extern "C" void kernel_launch(void* const* d_in, const int* in_sizes, int n_in,
                              void* d_out, int out_size, void* d_ws, size_t ws_size,
                              hipStream_t stream) {
  const float* x = (const float*)d_in[0];
  const int* pos = (const int*)d_in[1];
  const float* Wq = (const float*)d_in[2];
  const float* bq = (const float*)d_in[3];
  const float* Wk = (const float*)d_in[4];
  const float* bk = (const float*)d_in[5];
  const float* Wv = (const float*)d_in[6];
  const float* bv = (const float*)d_in[7];
  const float* Wo = (const float*)d_in[8];
  const float* bo = (const float*)d_in[9];
  float* out = (float*)d_out;

  char* p = (char*)d_ws;
  auto alloc = [&](size_t bytes) {
    char* rp = p;
    p += (bytes + 255) & ~(size_t)255;
    return rp;
  };
  const size_t XB = (size_t)M_ * E_ * sizeof(bf16);        // 8 MiB
  const size_t WB = (size_t)E_ * E_ * sizeof(bf16);        // 2 MiB
  const size_t TB = (size_t)B_ * S_ * NT2 * sizeof(float); // 256 KiB
  bf16* Xh = (bf16*)alloc(XB);
  bf16* Xl = (bf16*)alloc(XB);
  bf16* WqTh = (bf16*)alloc(WB); bf16* WqTl = (bf16*)alloc(WB);
  bf16* WkTh = (bf16*)alloc(WB); bf16* WkTl = (bf16*)alloc(WB);
  bf16* WvTh = (bf16*)alloc(WB); bf16* WvTl = (bf16*)alloc(WB);
  bf16* WoTh = (bf16*)alloc(WB); bf16* WoTl = (bf16*)alloc(WB);
  float* cosT = (float*)alloc(TB);
  float* sinT = (float*)alloc(TB);
  bf16* Qh = (bf16*)alloc(XB); bf16* Qlo = (bf16*)alloc(XB);
  bf16* Kh = (bf16*)alloc(XB); bf16* Klo = (bf16*)alloc(XB);
  bf16* VTb = (bf16*)alloc(XB);
  // ctx aliases X (X is dead after the QKV GEMM; attn runs after on same stream)
  bf16* Ch = Xh;
  bf16* Cl = Xl;

  split_f32_kernel<<<M_ * E_ / 4 / 256, 256, 0, stream>>>(x, Xh, Xl, M_ * E_ / 4);
  dim3 tg(32, 32);
  transpose_split_kernel<<<tg, 256, 0, stream>>>(Wq, WqTh, WqTl);
  transpose_split_kernel<<<tg, 256, 0, stream>>>(Wk, WkTh, WkTl);
  transpose_split_kernel<<<tg, 256, 0, stream>>>(Wv, WvTh, WvTl);
  transpose_split_kernel<<<tg, 256, 0, stream>>>(Wo, WoTh, WoTl);
  rope_tab_kernel<<<B_ * S_ * NT2 / 256, 256, 0, stream>>>(pos, cosT, sinT);

  dim3 gq(24, 32);
  gemm_qkv_kernel<<<gq, 256, 0, stream>>>(Xh, Xl, WqTh, WqTl, WkTh, WkTl, WvTh,
                                          WvTl, bq, bk, bv, cosT, sinT, Qh, Qlo,
                                          Kh, Klo, VTb);

  attn_kernel<<<B_ * H_ * (S_ / 128), 256, 0, stream>>>(Qh, Qlo, Kh, Klo, VTb,
                                                        Ch, Cl);

  dim3 go(8, 32);
  gemm_o_kernel<<<go, 256, 0, stream>>>(Ch, Cl, WoTh, WoTl, bo, out);
}

// Round 6
// 245.256 us; speedup vs baseline: 1.0643x; 1.0643x over previous
//
#include <hip/hip_runtime.h>
#include <hip/hip_bf16.h>
#include <math.h>

#define B_ 2
#define S_ 2048
#define E_ 1024
#define H_ 16
#define D_ 64
#define M_ 4096   // B_*S_
#define NT2 32    // D_/2
#define KVB 64

typedef __bf16 bf16;
typedef __bf16 bf16x4 __attribute__((ext_vector_type(4)));
typedef __bf16 bf16x8 __attribute__((ext_vector_type(8)));
typedef float f32x4 __attribute__((ext_vector_type(4)));
typedef float f32x16 __attribute__((ext_vector_type(16)));

__device__ __forceinline__ void gload_lds16(const void* g, void* lds) {
  __builtin_amdgcn_global_load_lds(
      (const __attribute__((address_space(1))) unsigned int*)g,
      (__attribute__((address_space(3))) unsigned int*)lds, 16, 0, 0);
}

#define MFMA16(a, b, c) __builtin_amdgcn_mfma_f32_16x16x32_bf16(a, b, c, 0, 0, 0)
#define MFMA32(a, b, c) __builtin_amdgcn_mfma_f32_32x32x16_bf16(a, b, c, 0, 0, 0)
#define FENCE asm volatile("" ::: "memory")

// ---------------- split fp32 -> bf16 hi/lo ----------------
__global__ __launch_bounds__(256)
void split_f32_kernel(const float* __restrict__ in, bf16* __restrict__ hi,
                      bf16* __restrict__ lo, int n4) {
  int i = blockIdx.x * 256 + threadIdx.x;
  if (i >= n4) return;
  float4 v = ((const float4*)in)[i];
  bf16 h0 = (bf16)v.x, h1 = (bf16)v.y, h2 = (bf16)v.z, h3 = (bf16)v.w;
  bf16x4 hv = {h0, h1, h2, h3};
  bf16x4 lv = {(bf16)(v.x - (float)h0), (bf16)(v.y - (float)h1),
               (bf16)(v.z - (float)h2), (bf16)(v.w - (float)h3)};
  *(bf16x4*)(hi + 4 * (size_t)i) = hv;
  *(bf16x4*)(lo + 4 * (size_t)i) = lv;
}

// ---------------- transpose + split W [K][N] -> T[N][K] hi/lo ----------------
__global__ __launch_bounds__(256)
void transpose_split_kernel(const float* __restrict__ W, bf16* __restrict__ Th,
                            bf16* __restrict__ Tl) {
  __shared__ float tile[32][33];
  const int tx = threadIdx.x & 31, ty = threadIdx.x >> 5;  // ty 0..7
  const int c0 = blockIdx.x * 32, r0 = blockIdx.y * 32;
#pragma unroll
  for (int i = 0; i < 4; ++i)
    tile[ty + 8 * i][tx] = W[(size_t)(r0 + ty + 8 * i) * E_ + c0 + tx];
  __syncthreads();
#pragma unroll
  for (int i = 0; i < 4; ++i) {
    int rr = ty + 8 * i;
    float v = tile[tx][rr];  // = W[r0+tx][c0+rr]
    bf16 hv = (bf16)v;
    size_t oidx = (size_t)(c0 + rr) * E_ + r0 + tx;
    Th[oidx] = hv;
    Tl[oidx] = (bf16)(v - (float)hv);
  }
}

// ---------------- RoPE cos/sin table ----------------
__global__ __launch_bounds__(256)
void rope_tab_kernel(const int* __restrict__ pos, float* __restrict__ cosT,
                     float* __restrict__ sinT) {
  int idx = blockIdx.x * 256 + threadIdx.x;  // B_*S_*NT2
  int t = idx & 31, bs = idx >> 5;
  double th = pow(10000.0, -(double)(2 * t) / 64.0);
  float ang = (float)pos[bs] * (float)th;  // fp32 product (matches ref rounding)
  double a = (double)ang;
  cosT[idx] = (float)cos(a);
  sinT[idx] = (float)sin(a);
}

// ---------------- fused QKV split-bf16 GEMM ----------------
// LDS tiles [128][32]bf16, slot-swizzled (u ^= (row>>1)&3) via pre-swizzled
// global source; fragment reads XOR the same sigma.
// Pipeline: dbuf + COUNTED vmcnt(8) (prev tile's 8 loads; this tile's 8 stay
// in flight across the raw s_barrier) — never drains to 0 in the main loop.
// Grid is 1D, XCD-chunked: each XCD owns 3 n-panels x all m, so its W share
// (1.5 MB) stays L2-resident and co-resident blocks share W k-tiles.
#define BMg 128
#define BNg 128
#define BKg 32

__global__ __launch_bounds__(256)
void gemm_qkv_kernel(const bf16* __restrict__ Ah_g, const bf16* __restrict__ Al_g,
                     const bf16* __restrict__ BhQ, const bf16* __restrict__ BlQ,
                     const bf16* __restrict__ BhK, const bf16* __restrict__ BlK,
                     const bf16* __restrict__ BhV, const bf16* __restrict__ BlV,
                     const float* __restrict__ bqp, const float* __restrict__ bkp,
                     const float* __restrict__ bvp,
                     const float* __restrict__ cosT, const float* __restrict__ sinT,
                     bf16* __restrict__ Qh, bf16* __restrict__ Qlo,
                     bf16* __restrict__ Kh, bf16* __restrict__ Klo,
                     bf16* __restrict__ VTb) {
  __shared__ bf16 lA_h[2][BMg * BKg], lA_l[2][BMg * BKg];
  __shared__ bf16 lB_h[2][BNg * BKg], lB_l[2][BNg * BKg];
  const int tid = threadIdx.x;
  const int lin = blockIdx.x;                 // 0..767
  const int cc = (lin & 7) * 96 + (lin >> 3); // XCD-chunk (768 = 8*96)
  const int nb = cc >> 5;                     // 0..23: consecutive cc share n
  const int mb = cc & 31;
  const int third = nb >> 3;                  // 0=Q 1=K 2=V
  const int n0 = (nb & 7) * BNg;
  const int m0 = mb * BMg;
  const bf16* Bh_g = third == 0 ? BhQ : third == 1 ? BhK : BhV;
  const bf16* Bl_g = third == 0 ? BlQ : third == 1 ? BlK : BlV;
  const float* bias = third == 0 ? bqp : third == 1 ? bkp : bvp;
  const int wave = tid >> 6, lane = tid & 63;
  const int wr = wave >> 1, wc = wave & 1;
  const int r = lane & 31, half = lane >> 5;
  const int KD = 1024;
  const int NK = KD / BKg;

  f32x16 acc[2][2] = {};

  auto stage = [&](int kt, int buf) {  // 8 gload_lds16 per thread
    const int k0 = kt * BKg;
    const bf16* gsrc[4] = {Ah_g, Al_g, Bh_g, Bl_g};
    bf16* ldst[4] = {&lA_h[buf][0], &lA_l[buf][0], &lB_h[buf][0], &lB_l[buf][0]};
    const int rs[4] = {m0, m0, n0, n0};
#pragma unroll
    for (int mm = 0; mm < 4; ++mm) {
#pragma unroll
      for (int i = 0; i < 2; ++i) {
        int c = i * 256 + tid;
        int row = c >> 2, u = c & 3;
        int us = u ^ ((row >> 1) & 3);  // pre-swizzled source slot
        const char* gp =
            (const char*)(gsrc[mm] + (size_t)(rs[mm] + row) * KD + k0) + us * 16;
        char* lp = (char*)ldst[mm] + (size_t)(i * 256 + wave * 64) * 16;
        gload_lds16(gp, lp);
      }
    }
  };

  auto compute = [&](int buf) {
#pragma unroll
    for (int ks = 0; ks < 2; ++ks) {
      bf16x8 a_h[2], a_l[2], b_h[2], b_l[2];
#pragma unroll
      for (int mi = 0; mi < 2; ++mi) {
        int row = wr * 64 + mi * 32 + r;
        int boff = row * 64 + ((ks * 32 + half * 16) ^ (((row >> 1) & 3) << 4));
        a_h[mi] = *(const bf16x8*)((const char*)&lA_h[buf][0] + boff);
        a_l[mi] = *(const bf16x8*)((const char*)&lA_l[buf][0] + boff);
      }
#pragma unroll
      for (int ni = 0; ni < 2; ++ni) {
        int row = wc * 64 + ni * 32 + r;
        int boff = row * 64 + ((ks * 32 + half * 16) ^ (((row >> 1) & 3) << 4));
        b_h[ni] = *(const bf16x8*)((const char*)&lB_h[buf][0] + boff);
        b_l[ni] = *(const bf16x8*)((const char*)&lB_l[buf][0] + boff);
      }
#pragma unroll
      for (int mi = 0; mi < 2; ++mi)
#pragma unroll
        for (int ni = 0; ni < 2; ++ni) {
          acc[mi][ni] = MFMA32(a_h[mi], b_h[ni], acc[mi][ni]);
          acc[mi][ni] = MFMA32(a_h[mi], b_l[ni], acc[mi][ni]);
          acc[mi][ni] = MFMA32(a_l[mi], b_h[ni], acc[mi][ni]);
        }
    }
  };

  stage(0, 0);
  int cur = 0;
  for (int kt = 0; kt < NK - 1; ++kt) {
    stage(kt + 1, cur ^ 1);
    asm volatile("s_waitcnt vmcnt(8)" ::: "memory");  // prev tile landed
    __builtin_amdgcn_s_barrier();
    FENCE;
    compute(cur);
    FENCE;
    __builtin_amdgcn_s_barrier();  // all reads done; buf[cur] may be re-staged
    FENCE;
    cur ^= 1;
  }
  asm volatile("s_waitcnt vmcnt(0)" ::: "memory");
  __builtin_amdgcn_s_barrier();
  FENCE;
  compute(cur);

  // ---- epilogue ----
#pragma unroll
  for (int mi = 0; mi < 2; ++mi)
#pragma unroll
    for (int ni = 0; ni < 2; ++ni) {
      const int gcol = n0 + wc * 64 + ni * 32 + r;
      const float bv = bias[gcol];
      if (third < 2) {  // Q or K: RoPE (+scale for Q), split
        bf16* outH = third == 0 ? Qh : Kh;
        bf16* outL = third == 0 ? Qlo : Klo;
        const int h = gcol >> 6, d = gcol & 63, tt = d >> 1;
#pragma unroll
        for (int tq = 0; tq < 4; ++tq) {
#pragma unroll
          for (int u = 0; u < 4; ++u) {
            int reg = tq * 4 + u;
            int grow = m0 + wr * 64 + mi * 32 + (u + 8 * tq + 4 * half);
            int s = grow & (S_ - 1), b = grow >> 11;
            float v = acc[mi][ni][reg] + bv;
            float other = __shfl_xor(v, 1);  // partner dim (d^1)
            float cs = cosT[(size_t)(b * S_ + s) * NT2 + tt];
            float sn = sinT[(size_t)(b * S_ + s) * NT2 + tt];
            float vr = (d & 1) ? (other * sn + v * cs) : (v * cs - other * sn);
            if (third == 0) vr *= 0.125f;  // 1/sqrt(D)
            bf16 hv = (bf16)vr;
            bf16 lv = (bf16)(vr - (float)hv);
            size_t idx = (((size_t)(b * H_ + h)) * S_ + s) * D_ + d;
            outH[idx] = hv;
            outL[idx] = lv;
          }
        }
      } else {  // V: bf16, transposed [B,H,D,S]
        const int h = gcol >> 6, d = gcol & 63;
#pragma unroll
        for (int tq = 0; tq < 4; ++tq) {
          int grow = m0 + wr * 64 + mi * 32 + (8 * tq + 4 * half);
          int s = grow & (S_ - 1), b = grow >> 11;
          ushort4 pk;
          unsigned short* pp = (unsigned short*)&pk;
#pragma unroll
          for (int u = 0; u < 4; ++u) {
            float v = acc[mi][ni][tq * 4 + u] + bv;
            bf16 hv = (bf16)v;
            pp[u] = __builtin_bit_cast(unsigned short, hv);
          }
          *(ushort4*)((unsigned short*)VTb +
                      (((size_t)(b * H_ + h)) * D_ + d) * S_ + s) = pk;
        }
      }
    }
}

// ---------------- O-projection split-bf16 GEMM ----------------
__global__ __launch_bounds__(256)
void gemm_o_kernel(const bf16* __restrict__ Ah_g, const bf16* __restrict__ Al_g,
                   const bf16* __restrict__ Bh_g, const bf16* __restrict__ Bl_g,
                   const float* __restrict__ bias, float* __restrict__ outF) {
  __shared__ bf16 lA_h[2][BMg * BKg], lA_l[2][BMg * BKg];
  __shared__ bf16 lB_h[2][BNg * BKg], lB_l[2][BNg * BKg];
  const int tid = threadIdx.x;
  const int lin = blockIdx.x;                 // 0..255
  const int cc = (lin & 7) * 32 + (lin >> 3); // XCD-chunk (256 = 8*32)
  const int nb = cc >> 5;                     // 0..7
  const int mb = cc & 31;
  const int m0 = mb * BMg, n0 = nb * BNg;
  const int wave = tid >> 6, lane = tid & 63;
  const int wr = wave >> 1, wc = wave & 1;
  const int r = lane & 31, half = lane >> 5;
  const int KD = 1024;
  const int NK = KD / BKg;

  f32x16 acc[2][2] = {};

  auto stage = [&](int kt, int buf) {
    const int k0 = kt * BKg;
    const bf16* gsrc[4] = {Ah_g, Al_g, Bh_g, Bl_g};
    bf16* ldst[4] = {&lA_h[buf][0], &lA_l[buf][0], &lB_h[buf][0], &lB_l[buf][0]};
    const int rs[4] = {m0, m0, n0, n0};
#pragma unroll
    for (int mm = 0; mm < 4; ++mm) {
#pragma unroll
      for (int i = 0; i < 2; ++i) {
        int c = i * 256 + tid;
        int row = c >> 2, u = c & 3;
        int us = u ^ ((row >> 1) & 3);
        const char* gp =
            (const char*)(gsrc[mm] + (size_t)(rs[mm] + row) * KD + k0) + us * 16;
        char* lp = (char*)ldst[mm] + (size_t)(i * 256 + wave * 64) * 16;
        gload_lds16(gp, lp);
      }
    }
  };

  auto compute = [&](int buf) {
#pragma unroll
    for (int ks = 0; ks < 2; ++ks) {
      bf16x8 a_h[2], a_l[2], b_h[2], b_l[2];
#pragma unroll
      for (int mi = 0; mi < 2; ++mi) {
        int row = wr * 64 + mi * 32 + r;
        int boff = row * 64 + ((ks * 32 + half * 16) ^ (((row >> 1) & 3) << 4));
        a_h[mi] = *(const bf16x8*)((const char*)&lA_h[buf][0] + boff);
        a_l[mi] = *(const bf16x8*)((const char*)&lA_l[buf][0] + boff);
      }
#pragma unroll
      for (int ni = 0; ni < 2; ++ni) {
        int row = wc * 64 + ni * 32 + r;
        int boff = row * 64 + ((ks * 32 + half * 16) ^ (((row >> 1) & 3) << 4));
        b_h[ni] = *(const bf16x8*)((const char*)&lB_h[buf][0] + boff);
        b_l[ni] = *(const bf16x8*)((const char*)&lB_l[buf][0] + boff);
      }
#pragma unroll
      for (int mi = 0; mi < 2; ++mi)
#pragma unroll
        for (int ni = 0; ni < 2; ++ni) {
          acc[mi][ni] = MFMA32(a_h[mi], b_h[ni], acc[mi][ni]);
          acc[mi][ni] = MFMA32(a_h[mi], b_l[ni], acc[mi][ni]);
          acc[mi][ni] = MFMA32(a_l[mi], b_h[ni], acc[mi][ni]);
        }
    }
  };

  stage(0, 0);
  int cur = 0;
  for (int kt = 0; kt < NK - 1; ++kt) {
    stage(kt + 1, cur ^ 1);
    asm volatile("s_waitcnt vmcnt(8)" ::: "memory");
    __builtin_amdgcn_s_barrier();
    FENCE;
    compute(cur);
    FENCE;
    __builtin_amdgcn_s_barrier();
    FENCE;
    cur ^= 1;
  }
  asm volatile("s_waitcnt vmcnt(0)" ::: "memory");
  __builtin_amdgcn_s_barrier();
  FENCE;
  compute(cur);

#pragma unroll
  for (int mi = 0; mi < 2; ++mi)
#pragma unroll
    for (int ni = 0; ni < 2; ++ni) {
      const int gcol = n0 + wc * 64 + ni * 32 + r;
      const float bv = bias[gcol];
#pragma unroll
      for (int tq = 0; tq < 4; ++tq)
#pragma unroll
        for (int u = 0; u < 4; ++u) {
          int grow = m0 + wr * 64 + mi * 32 + (u + 8 * tq + 4 * half);
          outF[(size_t)grow * E_ + gcol] = acc[mi][ni][tq * 4 + u] + bv;
        }
    }
}

// ---------------- flash attention (in-register softmax, swapped QK^T) -------
// Q,K: [B,H,S,D] bf16 hi/lo (Q pre-scaled by 1/8).  VT: [B,H,D,S] bf16.
// Out: ctx split hi/lo, layout [B,S,H,D].
// Swapped QK^T: S[key][q] -> each lane holds 16 scores for ONE q (=lane&15).
// Defer-max (THR=8): fast path has zero cross-lane ops; l kept per-lane.
// P stays in registers (scalar bf16 casts -> PV A-frags).
// V LDS columns stored in pa's key order sigma; register-staged (T14 split).
__global__ __launch_bounds__(256)
void attn_kernel(const bf16* __restrict__ Qh, const bf16* __restrict__ Ql,
                 const bf16* __restrict__ Kh, const bf16* __restrict__ Kl,
                 const bf16* __restrict__ VT, bf16* __restrict__ Ch,
                 bf16* __restrict__ Cl) {
  __shared__ bf16 sKh[2][KVB * 64];
  __shared__ bf16 sKl[2][KVB * 64];
  __shared__ bf16 sV[2][KVB * 64];  // [d=64][key-pos=64], row-XOR-swizzled

  const int tid = threadIdx.x;
  const int wave = tid >> 6, lane = tid & 63;
  const int r = lane & 15, hq = lane >> 4;
  const int bid = blockIdx.x;
  const int swz = (bid & 7) * 64 + (bid >> 3);  // XCD-chunked (512 % 8 == 0)
  const int bh = swz >> 4, qblk = swz & 15;
  const int q0 = qblk * 128 + wave * 32;
  const size_t hb = (size_t)bh * (S_ * D_);
  const size_t vb = (size_t)bh * (D_ * S_);

  // Q fragments in registers (B-operand of swapped QK^T; layout unchanged)
  bf16x8 qh[2][2], ql[2][2];
#pragma unroll
  for (int mi = 0; mi < 2; ++mi)
#pragma unroll
    for (int ks = 0; ks < 2; ++ks) {
      size_t off = hb + (size_t)(q0 + mi * 16 + r) * D_ + ks * 32 + hq * 8;
      qh[mi][ks] = *(const bf16x8*)&Qh[off];
      ql[mi][ks] = *(const bf16x8*)&Ql[off];
    }

  float m_lane[2] = {-1e30f, -1e30f};  // running max for q = r, per mi
  float l_lane[2] = {0.f, 0.f};        // per-lane partial denominator
  f32x4 o[2][4] = {};

  // K staging: global_load_lds, XOR-swizzled via pre-swizzled source chunks
  auto stageK = [&](int kt, int buf) {
    const bf16* kbh = Kh + hb + (size_t)kt * (KVB * D_);
    const bf16* kbl = Kl + hb + (size_t)kt * (KVB * D_);
#pragma unroll
    for (int i = 0; i < 2; ++i) {
      int c = i * 256 + tid;
      int ldo = (i * 256 + wave * 64) * 16;
      int cs = c ^ ((c >> 3) & 7);
      gload_lds16(kbh + cs * 8, (char*)&sKh[buf][0] + ldo);
      gload_lds16(kbl + cs * 8, (char*)&sKl[buf][0] + ldo);
    }
  };
  // V staging part 1: issue global loads into registers
  uint4 vld[2];
  auto loadV = [&](int kt) {
    const bf16* vbp = VT + vb + kt * KVB;
#pragma unroll
    for (int i = 0; i < 2; ++i) {
      int c = i * 256 + tid;
      int row = c >> 3, w = c & 7;  // row = d, w = key-chunk
      vld[i] = *(const uint4*)(vbp + (size_t)row * S_ + w * 8);
    }
  };
  // V staging part 2: ds_write in permuted-column order + row-XOR swizzle
  auto writeV = [&](int buf) {
#pragma unroll
    for (int i = 0; i < 2; ++i) {
      int c = i * 256 + tid;
      int row = c >> 3, w = c & 7;
      int pb0 = (w >> 2) * 32 + (w & 1) * 16 + ((w >> 1) & 1) * 4;  // elems
      char* base = (char*)&sV[buf][0] + row * 128;
      uint2 lo = {vld[i].x, vld[i].y};  // keys w*8+0..3 -> pos pb0..pb0+3
      uint2 hi = {vld[i].z, vld[i].w};  // keys w*8+4..7 -> pos pb0+8..pb0+11
      *(uint2*)(base + ((pb0 * 2) ^ ((row & 7) << 4))) = lo;
      *(uint2*)(base + (((pb0 + 8) * 2) ^ ((row & 7) << 4))) = hi;
    }
  };

  stageK(0, 0);
  loadV(0);
  writeV(0);
  __syncthreads();
  int cur = 0;

  for (int kt = 0; kt < S_ / KVB; ++kt) {
    if (kt + 1 < S_ / KVB) {
      stageK(kt + 1, cur ^ 1);
      loadV(kt + 1);  // issue early; write after PV (latency hidden)
    }

    // ---- QK^T (swapped: A=K, B=Q) -> sf[mi][nf][j]: key nf*16+hq*4+j, q=r
    f32x4 sf[2][4] = {};
#pragma unroll
    for (int nf = 0; nf < 4; ++nf)
#pragma unroll
      for (int ks = 0; ks < 2; ++ks) {
        int kk = nf * 16 + r;
        int boff = (kk * 128 + ks * 64 + hq * 16) ^ ((kk & 7) << 4);
        bf16x8 kkh = *(const bf16x8*)((const char*)&sKh[cur][0] + boff);
        bf16x8 kkl = *(const bf16x8*)((const char*)&sKl[cur][0] + boff);
#pragma unroll
        for (int mi = 0; mi < 2; ++mi) {
          sf[mi][nf] = MFMA16(kkh, qh[mi][ks], sf[mi][nf]);
          sf[mi][nf] = MFMA16(kkh, ql[mi][ks], sf[mi][nf]);
          sf[mi][nf] = MFMA16(kkl, qh[mi][ks], sf[mi][nf]);
        }
      }

    // ---- defer-max online softmax (lane-local fast path) ----
    float lmax[2];
#pragma unroll
    for (int mi = 0; mi < 2; ++mi) {
      f32x4 m4;
#pragma unroll
      for (int e = 0; e < 4; ++e)
        m4[e] = fmaxf(fmaxf(sf[mi][0][e], sf[mi][1][e]),
                      fmaxf(sf[mi][2][e], sf[mi][3][e]));
      lmax[mi] = fmaxf(fmaxf(m4[0], m4[1]), fmaxf(m4[2], m4[3]));
    }
    int need = (lmax[0] > m_lane[0] + 8.f) || (lmax[1] > m_lane[1] + 8.f);
    if (__any(need)) {  // slow path: recompute full max, rescale o & l
#pragma unroll
      for (int mi = 0; mi < 2; ++mi) {
        float mx = lmax[mi];
        mx = fmaxf(mx, __shfl_xor(mx, 16));
        mx = fmaxf(mx, __shfl_xor(mx, 32));
        float mn = fmaxf(m_lane[mi], mx);
        float al = __expf(m_lane[mi] - mn);
        l_lane[mi] *= al;
        m_lane[mi] = mn;
        int alb = __builtin_bit_cast(int, al);
#pragma unroll
        for (int j = 0; j < 4; ++j) {
          int g = __builtin_amdgcn_ds_bpermute((hq * 4 + j) * 4, alb);
          float a = __builtin_bit_cast(float, g);
#pragma unroll
          for (int nd = 0; nd < 4; ++nd) o[mi][nd][j] *= a;
        }
      }
    }
    // exp + per-lane partial l + pa fragments (P in registers)
    bf16x8 pa[2][2];
#pragma unroll
    for (int mi = 0; mi < 2; ++mi) {
      f32x4 s4 = {};
#pragma unroll
      for (int nf = 0; nf < 4; ++nf)
#pragma unroll
        for (int e = 0; e < 4; ++e) {
          float pv = __expf(sf[mi][nf][e] - m_lane[mi]);
          sf[mi][nf][e] = pv;
          s4[e] += pv;
        }
      l_lane[mi] += s4[0] + s4[1] + s4[2] + s4[3];
#pragma unroll
      for (int ks = 0; ks < 2; ++ks) {
        bf16x8 t;
#pragma unroll
        for (int e = 0; e < 4; ++e) {
          t[e] = (bf16)sf[mi][2 * ks][e];
          t[4 + e] = (bf16)sf[mi][2 * ks + 1][e];
        }
        pa[mi][ks] = t;
      }
    }

    // ---- PV: B-frags from sV (permuted cols match pa key order) ----
#pragma unroll
    for (int nd = 0; nd < 4; ++nd)
#pragma unroll
      for (int ks = 0; ks < 2; ++ks) {
        int dd = nd * 16 + r;
        int boff = (dd * 128 + ks * 64 + hq * 16) ^ ((dd & 7) << 4);
        bf16x8 vv = *(const bf16x8*)((const char*)&sV[cur][0] + boff);
#pragma unroll
        for (int mi = 0; mi < 2; ++mi)
          o[mi][nd] = MFMA16(pa[mi][ks], vv, o[mi][nd]);
      }

    if (kt + 1 < S_ / KVB) writeV(cur ^ 1);  // sV[cur^1] unread this iter
    __syncthreads();  // drains vmcnt(0)/lgkmcnt(0): next tile ready
    cur ^= 1;
  }

  // ---- epilogue: reduce l, broadcast to o-lanes, normalize, split, store ---
  const int b = bh >> 4, h = bh & 15;
  float lq[2][4];
#pragma unroll
  for (int mi = 0; mi < 2; ++mi) {
    float lr = l_lane[mi];
    lr += __shfl_xor(lr, 16);
    lr += __shfl_xor(lr, 32);
    int lb = __builtin_bit_cast(int, lr);
#pragma unroll
    for (int j = 0; j < 4; ++j) {
      int g = __builtin_amdgcn_ds_bpermute((hq * 4 + j) * 4, lb);
      lq[mi][j] = __builtin_bit_cast(float, g);
    }
  }
#pragma unroll
  for (int mi = 0; mi < 2; ++mi)
#pragma unroll
    for (int nd = 0; nd < 4; ++nd)
#pragma unroll
      for (int j = 0; j < 4; ++j) {
        int s = q0 + mi * 16 + hq * 4 + j;
        int d = nd * 16 + r;
        float ov = o[mi][nd][j] / lq[mi][j];
        bf16 hv = (bf16)ov;
        bf16 lv = (bf16)(ov - (float)hv);
        size_t idx = (((size_t)(b * S_ + s)) * H_ + h) * D_ + d;
        Ch[idx] = hv;
        Cl[idx] = lv;
      }
}

// ---------------- host ----------------
extern "C" void kernel_launch(void* const* d_in, const int* in_sizes, int n_in,
                              void* d_out, int out_size, void* d_ws, size_t ws_size,
                              hipStream_t stream) {
  const float* x = (const float*)d_in[0];
  const int* pos = (const int*)d_in[1];
  const float* Wq = (const float*)d_in[2];
  const float* bq = (const float*)d_in[3];
  const float* Wk = (const float*)d_in[4];
  const float* bk = (const float*)d_in[5];
  const float* Wv = (const float*)d_in[6];
  const float* bv = (const float*)d_in[7];
  const float* Wo = (const float*)d_in[8];
  const float* bo = (const float*)d_in[9];
  float* out = (float*)d_out;

  char* p = (char*)d_ws;
  auto alloc = [&](size_t bytes) {
    char* rp = p;
    p += (bytes + 255) & ~(size_t)255;
    return rp;
  };
  const size_t XB = (size_t)M_ * E_ * sizeof(bf16);        // 8 MiB
  const size_t WB = (size_t)E_ * E_ * sizeof(bf16);        // 2 MiB
  const size_t TB = (size_t)B_ * S_ * NT2 * sizeof(float); // 256 KiB
  bf16* Xh = (bf16*)alloc(XB);
  bf16* Xl = (bf16*)alloc(XB);
  bf16* WqTh = (bf16*)alloc(WB); bf16* WqTl = (bf16*)alloc(WB);
  bf16* WkTh = (bf16*)alloc(WB); bf16* WkTl = (bf16*)alloc(WB);
  bf16* WvTh = (bf16*)alloc(WB); bf16* WvTl = (bf16*)alloc(WB);
  bf16* WoTh = (bf16*)alloc(WB); bf16* WoTl = (bf16*)alloc(WB);
  float* cosT = (float*)alloc(TB);
  float* sinT = (float*)alloc(TB);
  bf16* Qh = (bf16*)alloc(XB); bf16* Qlo = (bf16*)alloc(XB);
  bf16* Kh = (bf16*)alloc(XB); bf16* Klo = (bf16*)alloc(XB);
  bf16* VTb = (bf16*)alloc(XB);
  // ctx aliases X (X is dead after the QKV GEMM; attn runs after on same stream)
  bf16* Ch = Xh;
  bf16* Cl = Xl;

  split_f32_kernel<<<M_ * E_ / 4 / 256, 256, 0, stream>>>(x, Xh, Xl, M_ * E_ / 4);
  dim3 tg(32, 32);
  transpose_split_kernel<<<tg, 256, 0, stream>>>(Wq, WqTh, WqTl);
  transpose_split_kernel<<<tg, 256, 0, stream>>>(Wk, WkTh, WkTl);
  transpose_split_kernel<<<tg, 256, 0, stream>>>(Wv, WvTh, WvTl);
  transpose_split_kernel<<<tg, 256, 0, stream>>>(Wo, WoTh, WoTl);
  rope_tab_kernel<<<B_ * S_ * NT2 / 256, 256, 0, stream>>>(pos, cosT, sinT);

  gemm_qkv_kernel<<<768, 256, 0, stream>>>(Xh, Xl, WqTh, WqTl, WkTh, WkTl, WvTh,
                                           WvTl, bq, bk, bv, cosT, sinT, Qh, Qlo,
                                           Kh, Klo, VTb);

  attn_kernel<<<B_ * H_ * (S_ / 128), 256, 0, stream>>>(Qh, Qlo, Kh, Klo, VTb,
                                                        Ch, Cl);

  gemm_o_kernel<<<256, 256, 0, stream>>>(Ch, Cl, WoTh, WoTl, bo, out);
}

// Round 7
// 232.809 us; speedup vs baseline: 1.1212x; 1.0535x over previous
//
#include <hip/hip_runtime.h>
#include <hip/hip_bf16.h>
#include <math.h>

#define B_ 2
#define S_ 2048
#define E_ 1024
#define H_ 16
#define D_ 64
#define M_ 4096   // B_*S_
#define NT2 32    // D_/2
#define KVB 64

typedef __bf16 bf16;
typedef __bf16 bf16x4 __attribute__((ext_vector_type(4)));
typedef __bf16 bf16x8 __attribute__((ext_vector_type(8)));
typedef float f32x4 __attribute__((ext_vector_type(4)));
typedef float f32x16 __attribute__((ext_vector_type(16)));

__device__ __forceinline__ void gload_lds16(const void* g, void* lds) {
  __builtin_amdgcn_global_load_lds(
      (const __attribute__((address_space(1))) unsigned int*)g,
      (__attribute__((address_space(3))) unsigned int*)lds, 16, 0, 0);
}

#define MFMA16(a, b, c) __builtin_amdgcn_mfma_f32_16x16x32_bf16(a, b, c, 0, 0, 0)
#define MFMA32(a, b, c) __builtin_amdgcn_mfma_f32_32x32x16_bf16(a, b, c, 0, 0, 0)
#define FENCE asm volatile("" ::: "memory")

// ---------------- split fp32 -> bf16 hi/lo ----------------
__global__ __launch_bounds__(256)
void split_f32_kernel(const float* __restrict__ in, bf16* __restrict__ hi,
                      bf16* __restrict__ lo, int n4) {
  int i = blockIdx.x * 256 + threadIdx.x;
  if (i >= n4) return;
  float4 v = ((const float4*)in)[i];
  bf16 h0 = (bf16)v.x, h1 = (bf16)v.y, h2 = (bf16)v.z, h3 = (bf16)v.w;
  bf16x4 hv = {h0, h1, h2, h3};
  bf16x4 lv = {(bf16)(v.x - (float)h0), (bf16)(v.y - (float)h1),
               (bf16)(v.z - (float)h2), (bf16)(v.w - (float)h3)};
  *(bf16x4*)(hi + 4 * (size_t)i) = hv;
  *(bf16x4*)(lo + 4 * (size_t)i) = lv;
}

// ---------------- transpose + split W [K][N] -> T[N][K] hi/lo ----------------
__global__ __launch_bounds__(256)
void transpose_split_kernel(const float* __restrict__ W, bf16* __restrict__ Th,
                            bf16* __restrict__ Tl) {
  __shared__ float tile[32][33];
  const int tx = threadIdx.x & 31, ty = threadIdx.x >> 5;  // ty 0..7
  const int c0 = blockIdx.x * 32, r0 = blockIdx.y * 32;
#pragma unroll
  for (int i = 0; i < 4; ++i)
    tile[ty + 8 * i][tx] = W[(size_t)(r0 + ty + 8 * i) * E_ + c0 + tx];
  __syncthreads();
#pragma unroll
  for (int i = 0; i < 4; ++i) {
    int rr = ty + 8 * i;
    float v = tile[tx][rr];  // = W[r0+tx][c0+rr]
    bf16 hv = (bf16)v;
    size_t oidx = (size_t)(c0 + rr) * E_ + r0 + tx;
    Th[oidx] = hv;
    Tl[oidx] = (bf16)(v - (float)hv);
  }
}

// ---------------- RoPE cos/sin table ----------------
__global__ __launch_bounds__(256)
void rope_tab_kernel(const int* __restrict__ pos, float* __restrict__ cosT,
                     float* __restrict__ sinT) {
  int idx = blockIdx.x * 256 + threadIdx.x;  // B_*S_*NT2
  int t = idx & 31, bs = idx >> 5;
  double th = pow(10000.0, -(double)(2 * t) / 64.0);
  float ang = (float)pos[bs] * (float)th;  // fp32 product (matches ref rounding)
  double a = (double)ang;
  cosT[idx] = (float)cos(a);
  sinT[idx] = (float)sin(a);
}

// ---------------- fused QKV split-bf16 GEMM, 256x256 tile ----------------
// 512 threads = 8 waves (2M x 4N), wave tile 128x64 (4mi x 2ni of 32x32).
// LDS tiles [256][32]bf16 x4 (A/B x hi/lo), dbuf = 128 KB.
// Slot-swizzle u ^= (row>>1)&3 via pre-swizzled global source (linear dest);
// fragment reads XOR the same sigma.  Sync: stage-ahead + counted vmcnt(8)
// + raw barriers (loads for tile t+1 stay in flight across the barrier).
// 4x MFMA work per K-step per SIMD vs the 128^2 tile + 2 waves/SIMD in-block
// overlap — attacks the 128^2 2-phase structural ceiling (~23% MfmaUtil).
#define BMq 256
#define BNq 256
#define BKq 32

__global__ __launch_bounds__(512, 2)
void gemm_qkv_kernel(const bf16* __restrict__ Ah_g, const bf16* __restrict__ Al_g,
                     const bf16* __restrict__ BhQ, const bf16* __restrict__ BlQ,
                     const bf16* __restrict__ BhK, const bf16* __restrict__ BlK,
                     const bf16* __restrict__ BhV, const bf16* __restrict__ BlV,
                     const float* __restrict__ bqp, const float* __restrict__ bkp,
                     const float* __restrict__ bvp,
                     const float* __restrict__ cosT, const float* __restrict__ sinT,
                     bf16* __restrict__ Qh, bf16* __restrict__ Qlo,
                     bf16* __restrict__ Kh, bf16* __restrict__ Klo,
                     bf16* __restrict__ VTb) {
  __shared__ bf16 lA_h[2][BMq * BKq], lA_l[2][BMq * BKq];  // 16KB per buf each
  __shared__ bf16 lB_h[2][BNq * BKq], lB_l[2][BNq * BKq];
  const int tid = threadIdx.x;                // 0..511
  const int lin = blockIdx.x;                 // 0..191
  const int cc = (lin & 7) * 24 + (lin >> 3); // XCD chunk (192 = 8*24)
  const int third = cc >> 6;                  // 0=Q 1=K 2=V
  const int rem = cc & 63;
  const int n0 = (rem >> 4) * BNq;            // 4 n-panels per third
  const int m0 = (rem & 15) * BMq;            // 16 m-panels
  const bf16* Bh_g = third == 0 ? BhQ : third == 1 ? BhK : BhV;
  const bf16* Bl_g = third == 0 ? BlQ : third == 1 ? BlK : BlV;
  const float* bias = third == 0 ? bqp : third == 1 ? bkp : bvp;
  const int wave = tid >> 6, lane = tid & 63;
  const int wr = wave >> 2, wc = wave & 3;    // 2M x 4N wave grid
  const int r = lane & 31, half = lane >> 5;
  const int KD = 1024;
  const int NK = KD / BKq;                    // 32

  f32x16 acc[4][2] = {};

  auto stage = [&](int kt, int buf) {  // 8 gload_lds16 per thread
    const int k0 = kt * BKq;
    const bf16* gsrc[4] = {Ah_g, Al_g, Bh_g, Bl_g};
    bf16* ldst[4] = {&lA_h[buf][0], &lA_l[buf][0], &lB_h[buf][0], &lB_l[buf][0]};
    const int rs[4] = {m0, m0, n0, n0};
#pragma unroll
    for (int mm = 0; mm < 4; ++mm) {
#pragma unroll
      for (int i = 0; i < 2; ++i) {
        int c = i * 512 + tid;          // chunk 0..1023 (16B each)
        int row = c >> 2, u = c & 3;
        int us = u ^ ((row >> 1) & 3);  // pre-swizzled source slot
        const char* gp =
            (const char*)(gsrc[mm] + (size_t)(rs[mm] + row) * KD + k0) + us * 16;
        char* lp = (char*)ldst[mm] + (size_t)(i * 512 + wave * 64) * 16;
        gload_lds16(gp, lp);
      }
    }
  };

  auto compute = [&](int buf) {
#pragma unroll
    for (int ks = 0; ks < 2; ++ks) {
      bf16x8 a_h[4], a_l[4], b_h[2], b_l[2];
#pragma unroll
      for (int mi = 0; mi < 4; ++mi) {
        int row = wr * 128 + mi * 32 + r;
        int boff = row * 64 + ((ks * 32 + half * 16) ^ (((row >> 1) & 3) << 4));
        a_h[mi] = *(const bf16x8*)((const char*)&lA_h[buf][0] + boff);
        a_l[mi] = *(const bf16x8*)((const char*)&lA_l[buf][0] + boff);
      }
#pragma unroll
      for (int ni = 0; ni < 2; ++ni) {
        int row = wc * 64 + ni * 32 + r;
        int boff = row * 64 + ((ks * 32 + half * 16) ^ (((row >> 1) & 3) << 4));
        b_h[ni] = *(const bf16x8*)((const char*)&lB_h[buf][0] + boff);
        b_l[ni] = *(const bf16x8*)((const char*)&lB_l[buf][0] + boff);
      }
#pragma unroll
      for (int mi = 0; mi < 4; ++mi)
#pragma unroll
        for (int ni = 0; ni < 2; ++ni) {
          acc[mi][ni] = MFMA32(a_h[mi], b_h[ni], acc[mi][ni]);
          acc[mi][ni] = MFMA32(a_h[mi], b_l[ni], acc[mi][ni]);
          acc[mi][ni] = MFMA32(a_l[mi], b_h[ni], acc[mi][ni]);
        }
    }
  };

  stage(0, 0);
  int cur = 0;
  for (int kt = 0; kt < NK - 1; ++kt) {
    stage(kt + 1, cur ^ 1);
    asm volatile("s_waitcnt vmcnt(8)" ::: "memory");  // prev tile landed
    __builtin_amdgcn_s_barrier();
    FENCE;
    compute(cur);
    FENCE;
    __builtin_amdgcn_s_barrier();  // all reads done; buf[cur] may be re-staged
    FENCE;
    cur ^= 1;
  }
  asm volatile("s_waitcnt vmcnt(0)" ::: "memory");
  __builtin_amdgcn_s_barrier();
  FENCE;
  compute(cur);

  // ---- epilogue ----
#pragma unroll
  for (int mi = 0; mi < 4; ++mi)
#pragma unroll
    for (int ni = 0; ni < 2; ++ni) {
      const int gcol = n0 + wc * 64 + ni * 32 + r;
      const float bv = bias[gcol];
      if (third < 2) {  // Q or K: RoPE (+scale for Q), split
        bf16* outH = third == 0 ? Qh : Kh;
        bf16* outL = third == 0 ? Qlo : Klo;
        const int h = gcol >> 6, d = gcol & 63, tt = d >> 1;
#pragma unroll
        for (int tq = 0; tq < 4; ++tq) {
#pragma unroll
          for (int u = 0; u < 4; ++u) {
            int reg = tq * 4 + u;
            int grow = m0 + wr * 128 + mi * 32 + (u + 8 * tq + 4 * half);
            int s = grow & (S_ - 1), b = grow >> 11;
            float v = acc[mi][ni][reg] + bv;
            float other = __shfl_xor(v, 1);  // partner dim (d^1)
            float cs = cosT[(size_t)(b * S_ + s) * NT2 + tt];
            float sn = sinT[(size_t)(b * S_ + s) * NT2 + tt];
            float vr = (d & 1) ? (other * sn + v * cs) : (v * cs - other * sn);
            if (third == 0) vr *= 0.125f;  // 1/sqrt(D)
            bf16 hv = (bf16)vr;
            bf16 lv = (bf16)(vr - (float)hv);
            size_t idx = (((size_t)(b * H_ + h)) * S_ + s) * D_ + d;
            outH[idx] = hv;
            outL[idx] = lv;
          }
        }
      } else {  // V: bf16, transposed [B,H,D,S]
        const int h = gcol >> 6, d = gcol & 63;
#pragma unroll
        for (int tq = 0; tq < 4; ++tq) {
          int grow = m0 + wr * 128 + mi * 32 + (8 * tq + 4 * half);
          int s = grow & (S_ - 1), b = grow >> 11;
          ushort4 pk;
          unsigned short* pp = (unsigned short*)&pk;
#pragma unroll
          for (int u = 0; u < 4; ++u) {
            float v = acc[mi][ni][tq * 4 + u] + bv;
            bf16 hv = (bf16)v;
            pp[u] = __builtin_bit_cast(unsigned short, hv);
          }
          *(ushort4*)((unsigned short*)VTb +
                      (((size_t)(b * H_ + h)) * D_ + d) * S_ + s) = pk;
        }
      }
    }
}

// ---------------- O-projection split-bf16 GEMM (128^2, unchanged) ----------
#define BMg 128
#define BNg 128
#define BKg 32

__global__ __launch_bounds__(256)
void gemm_o_kernel(const bf16* __restrict__ Ah_g, const bf16* __restrict__ Al_g,
                   const bf16* __restrict__ Bh_g, const bf16* __restrict__ Bl_g,
                   const float* __restrict__ bias, float* __restrict__ outF) {
  __shared__ bf16 lA_h[2][BMg * BKg], lA_l[2][BMg * BKg];
  __shared__ bf16 lB_h[2][BNg * BKg], lB_l[2][BNg * BKg];
  const int tid = threadIdx.x;
  const int lin = blockIdx.x;                 // 0..255
  const int cc = (lin & 7) * 32 + (lin >> 3); // XCD-chunk (256 = 8*32)
  const int nb = cc >> 5;                     // 0..7
  const int mb = cc & 31;
  const int m0 = mb * BMg, n0 = nb * BNg;
  const int wave = tid >> 6, lane = tid & 63;
  const int wr = wave >> 1, wc = wave & 1;
  const int r = lane & 31, half = lane >> 5;
  const int KD = 1024;
  const int NK = KD / BKg;

  f32x16 acc[2][2] = {};

  auto stage = [&](int kt, int buf) {
    const int k0 = kt * BKg;
    const bf16* gsrc[4] = {Ah_g, Al_g, Bh_g, Bl_g};
    bf16* ldst[4] = {&lA_h[buf][0], &lA_l[buf][0], &lB_h[buf][0], &lB_l[buf][0]};
    const int rs[4] = {m0, m0, n0, n0};
#pragma unroll
    for (int mm = 0; mm < 4; ++mm) {
#pragma unroll
      for (int i = 0; i < 2; ++i) {
        int c = i * 256 + tid;
        int row = c >> 2, u = c & 3;
        int us = u ^ ((row >> 1) & 3);
        const char* gp =
            (const char*)(gsrc[mm] + (size_t)(rs[mm] + row) * KD + k0) + us * 16;
        char* lp = (char*)ldst[mm] + (size_t)(i * 256 + wave * 64) * 16;
        gload_lds16(gp, lp);
      }
    }
  };

  auto compute = [&](int buf) {
#pragma unroll
    for (int ks = 0; ks < 2; ++ks) {
      bf16x8 a_h[2], a_l[2], b_h[2], b_l[2];
#pragma unroll
      for (int mi = 0; mi < 2; ++mi) {
        int row = wr * 64 + mi * 32 + r;
        int boff = row * 64 + ((ks * 32 + half * 16) ^ (((row >> 1) & 3) << 4));
        a_h[mi] = *(const bf16x8*)((const char*)&lA_h[buf][0] + boff);
        a_l[mi] = *(const bf16x8*)((const char*)&lA_l[buf][0] + boff);
      }
#pragma unroll
      for (int ni = 0; ni < 2; ++ni) {
        int row = wc * 64 + ni * 32 + r;
        int boff = row * 64 + ((ks * 32 + half * 16) ^ (((row >> 1) & 3) << 4));
        b_h[ni] = *(const bf16x8*)((const char*)&lB_h[buf][0] + boff);
        b_l[ni] = *(const bf16x8*)((const char*)&lB_l[buf][0] + boff);
      }
#pragma unroll
      for (int mi = 0; mi < 2; ++mi)
#pragma unroll
        for (int ni = 0; ni < 2; ++ni) {
          acc[mi][ni] = MFMA32(a_h[mi], b_h[ni], acc[mi][ni]);
          acc[mi][ni] = MFMA32(a_h[mi], b_l[ni], acc[mi][ni]);
          acc[mi][ni] = MFMA32(a_l[mi], b_h[ni], acc[mi][ni]);
        }
    }
  };

  stage(0, 0);
  int cur = 0;
  for (int kt = 0; kt < NK - 1; ++kt) {
    stage(kt + 1, cur ^ 1);
    asm volatile("s_waitcnt vmcnt(8)" ::: "memory");
    __builtin_amdgcn_s_barrier();
    FENCE;
    compute(cur);
    FENCE;
    __builtin_amdgcn_s_barrier();
    FENCE;
    cur ^= 1;
  }
  asm volatile("s_waitcnt vmcnt(0)" ::: "memory");
  __builtin_amdgcn_s_barrier();
  FENCE;
  compute(cur);

#pragma unroll
  for (int mi = 0; mi < 2; ++mi)
#pragma unroll
    for (int ni = 0; ni < 2; ++ni) {
      const int gcol = n0 + wc * 64 + ni * 32 + r;
      const float bv = bias[gcol];
#pragma unroll
      for (int tq = 0; tq < 4; ++tq)
#pragma unroll
        for (int u = 0; u < 4; ++u) {
          int grow = m0 + wr * 64 + mi * 32 + (u + 8 * tq + 4 * half);
          outF[(size_t)grow * E_ + gcol] = acc[mi][ni][tq * 4 + u] + bv;
        }
    }
}

// ---------------- flash attention (in-register softmax, swapped QK^T) -------
__global__ __launch_bounds__(256)
void attn_kernel(const bf16* __restrict__ Qh, const bf16* __restrict__ Ql,
                 const bf16* __restrict__ Kh, const bf16* __restrict__ Kl,
                 const bf16* __restrict__ VT, bf16* __restrict__ Ch,
                 bf16* __restrict__ Cl) {
  __shared__ bf16 sKh[2][KVB * 64];
  __shared__ bf16 sKl[2][KVB * 64];
  __shared__ bf16 sV[2][KVB * 64];  // [d=64][key-pos=64], row-XOR-swizzled

  const int tid = threadIdx.x;
  const int wave = tid >> 6, lane = tid & 63;
  const int r = lane & 15, hq = lane >> 4;
  const int bid = blockIdx.x;
  const int swz = (bid & 7) * 64 + (bid >> 3);  // XCD-chunked (512 % 8 == 0)
  const int bh = swz >> 4, qblk = swz & 15;
  const int q0 = qblk * 128 + wave * 32;
  const size_t hb = (size_t)bh * (S_ * D_);
  const size_t vb = (size_t)bh * (D_ * S_);

  // Q fragments in registers (B-operand of swapped QK^T; layout unchanged)
  bf16x8 qh[2][2], ql[2][2];
#pragma unroll
  for (int mi = 0; mi < 2; ++mi)
#pragma unroll
    for (int ks = 0; ks < 2; ++ks) {
      size_t off = hb + (size_t)(q0 + mi * 16 + r) * D_ + ks * 32 + hq * 8;
      qh[mi][ks] = *(const bf16x8*)&Qh[off];
      ql[mi][ks] = *(const bf16x8*)&Ql[off];
    }

  float m_lane[2] = {-1e30f, -1e30f};  // running max for q = r, per mi
  float l_lane[2] = {0.f, 0.f};        // per-lane partial denominator
  f32x4 o[2][4] = {};

  // K staging: global_load_lds, XOR-swizzled via pre-swizzled source chunks
  auto stageK = [&](int kt, int buf) {
    const bf16* kbh = Kh + hb + (size_t)kt * (KVB * D_);
    const bf16* kbl = Kl + hb + (size_t)kt * (KVB * D_);
#pragma unroll
    for (int i = 0; i < 2; ++i) {
      int c = i * 256 + tid;
      int ldo = (i * 256 + wave * 64) * 16;
      int cs = c ^ ((c >> 3) & 7);
      gload_lds16(kbh + cs * 8, (char*)&sKh[buf][0] + ldo);
      gload_lds16(kbl + cs * 8, (char*)&sKl[buf][0] + ldo);
    }
  };
  // V staging part 1: issue global loads into registers
  uint4 vld[2];
  auto loadV = [&](int kt) {
    const bf16* vbp = VT + vb + kt * KVB;
#pragma unroll
    for (int i = 0; i < 2; ++i) {
      int c = i * 256 + tid;
      int row = c >> 3, w = c & 7;  // row = d, w = key-chunk
      vld[i] = *(const uint4*)(vbp + (size_t)row * S_ + w * 8);
    }
  };
  // V staging part 2: ds_write in permuted-column order + row-XOR swizzle
  auto writeV = [&](int buf) {
#pragma unroll
    for (int i = 0; i < 2; ++i) {
      int c = i * 256 + tid;
      int row = c >> 3, w = c & 7;
      int pb0 = (w >> 2) * 32 + (w & 1) * 16 + ((w >> 1) & 1) * 4;  // elems
      char* base = (char*)&sV[buf][0] + row * 128;
      uint2 lo = {vld[i].x, vld[i].y};  // keys w*8+0..3 -> pos pb0..pb0+3
      uint2 hi = {vld[i].z, vld[i].w};  // keys w*8+4..7 -> pos pb0+8..pb0+11
      *(uint2*)(base + ((pb0 * 2) ^ ((row & 7) << 4))) = lo;
      *(uint2*)(base + (((pb0 + 8) * 2) ^ ((row & 7) << 4))) = hi;
    }
  };

  stageK(0, 0);
  loadV(0);
  writeV(0);
  __syncthreads();
  int cur = 0;

  for (int kt = 0; kt < S_ / KVB; ++kt) {
    if (kt + 1 < S_ / KVB) {
      stageK(kt + 1, cur ^ 1);
      loadV(kt + 1);  // issue early; write after PV (latency hidden)
    }

    // ---- QK^T (swapped: A=K, B=Q) -> sf[mi][nf][j]: key nf*16+hq*4+j, q=r
    f32x4 sf[2][4] = {};
#pragma unroll
    for (int nf = 0; nf < 4; ++nf)
#pragma unroll
      for (int ks = 0; ks < 2; ++ks) {
        int kk = nf * 16 + r;
        int boff = (kk * 128 + ks * 64 + hq * 16) ^ ((kk & 7) << 4);
        bf16x8 kkh = *(const bf16x8*)((const char*)&sKh[cur][0] + boff);
        bf16x8 kkl = *(const bf16x8*)((const char*)&sKl[cur][0] + boff);
#pragma unroll
        for (int mi = 0; mi < 2; ++mi) {
          sf[mi][nf] = MFMA16(kkh, qh[mi][ks], sf[mi][nf]);
          sf[mi][nf] = MFMA16(kkh, ql[mi][ks], sf[mi][nf]);
          sf[mi][nf] = MFMA16(kkl, qh[mi][ks], sf[mi][nf]);
        }
      }

    // ---- defer-max online softmax (lane-local fast path) ----
    float lmax[2];
#pragma unroll
    for (int mi = 0; mi < 2; ++mi) {
      f32x4 m4;
#pragma unroll
      for (int e = 0; e < 4; ++e)
        m4[e] = fmaxf(fmaxf(sf[mi][0][e], sf[mi][1][e]),
                      fmaxf(sf[mi][2][e], sf[mi][3][e]));
      lmax[mi] = fmaxf(fmaxf(m4[0], m4[1]), fmaxf(m4[2], m4[3]));
    }
    int need = (lmax[0] > m_lane[0] + 8.f) || (lmax[1] > m_lane[1] + 8.f);
    if (__any(need)) {  // slow path: recompute full max, rescale o & l
#pragma unroll
      for (int mi = 0; mi < 2; ++mi) {
        float mx = lmax[mi];
        mx = fmaxf(mx, __shfl_xor(mx, 16));
        mx = fmaxf(mx, __shfl_xor(mx, 32));
        float mn = fmaxf(m_lane[mi], mx);
        float al = __expf(m_lane[mi] - mn);
        l_lane[mi] *= al;
        m_lane[mi] = mn;
        int alb = __builtin_bit_cast(int, al);
#pragma unroll
        for (int j = 0; j < 4; ++j) {
          int g = __builtin_amdgcn_ds_bpermute((hq * 4 + j) * 4, alb);
          float a = __builtin_bit_cast(float, g);
#pragma unroll
          for (int nd = 0; nd < 4; ++nd) o[mi][nd][j] *= a;
        }
      }
    }
    // exp + per-lane partial l + pa fragments (P in registers)
    bf16x8 pa[2][2];
#pragma unroll
    for (int mi = 0; mi < 2; ++mi) {
      f32x4 s4 = {};
#pragma unroll
      for (int nf = 0; nf < 4; ++nf)
#pragma unroll
        for (int e = 0; e < 4; ++e) {
          float pv = __expf(sf[mi][nf][e] - m_lane[mi]);
          sf[mi][nf][e] = pv;
          s4[e] += pv;
        }
      l_lane[mi] += s4[0] + s4[1] + s4[2] + s4[3];
#pragma unroll
      for (int ks = 0; ks < 2; ++ks) {
        bf16x8 t;
#pragma unroll
        for (int e = 0; e < 4; ++e) {
          t[e] = (bf16)sf[mi][2 * ks][e];
          t[4 + e] = (bf16)sf[mi][2 * ks + 1][e];
        }
        pa[mi][ks] = t;
      }
    }

    // ---- PV: B-frags from sV (permuted cols match pa key order) ----
#pragma unroll
    for (int nd = 0; nd < 4; ++nd)
#pragma unroll
      for (int ks = 0; ks < 2; ++ks) {
        int dd = nd * 16 + r;
        int boff = (dd * 128 + ks * 64 + hq * 16) ^ ((dd & 7) << 4);
        bf16x8 vv = *(const bf16x8*)((const char*)&sV[cur][0] + boff);
#pragma unroll
        for (int mi = 0; mi < 2; ++mi)
          o[mi][nd] = MFMA16(pa[mi][ks], vv, o[mi][nd]);
      }

    if (kt + 1 < S_ / KVB) writeV(cur ^ 1);  // sV[cur^1] unread this iter
    __syncthreads();  // drains vmcnt(0)/lgkmcnt(0): next tile ready
    cur ^= 1;
  }

  // ---- epilogue: reduce l, broadcast to o-lanes, normalize, split, store ---
  const int b = bh >> 4, h = bh & 15;
  float lq[2][4];
#pragma unroll
  for (int mi = 0; mi < 2; ++mi) {
    float lr = l_lane[mi];
    lr += __shfl_xor(lr, 16);
    lr += __shfl_xor(lr, 32);
    int lb = __builtin_bit_cast(int, lr);
#pragma unroll
    for (int j = 0; j < 4; ++j) {
      int g = __builtin_amdgcn_ds_bpermute((hq * 4 + j) * 4, lb);
      lq[mi][j] = __builtin_bit_cast(float, g);
    }
  }
#pragma unroll
  for (int mi = 0; mi < 2; ++mi)
#pragma unroll
    for (int nd = 0; nd < 4; ++nd)
#pragma unroll
      for (int j = 0; j < 4; ++j) {
        int s = q0 + mi * 16 + hq * 4 + j;
        int d = nd * 16 + r;
        float ov = o[mi][nd][j] / lq[mi][j];
        bf16 hv = (bf16)ov;
        bf16 lv = (bf16)(ov - (float)hv);
        size_t idx = (((size_t)(b * S_ + s)) * H_ + h) * D_ + d;
        Ch[idx] = hv;
        Cl[idx] = lv;
      }
}

// ---------------- host ----------------
extern "C" void kernel_launch(void* const* d_in, const int* in_sizes, int n_in,
                              void* d_out, int out_size, void* d_ws, size_t ws_size,
                              hipStream_t stream) {
  const float* x = (const float*)d_in[0];
  const int* pos = (const int*)d_in[1];
  const float* Wq = (const float*)d_in[2];
  const float* bq = (const float*)d_in[3];
  const float* Wk = (const float*)d_in[4];
  const float* bk = (const float*)d_in[5];
  const float* Wv = (const float*)d_in[6];
  const float* bv = (const float*)d_in[7];
  const float* Wo = (const float*)d_in[8];
  const float* bo = (const float*)d_in[9];
  float* out = (float*)d_out;

  char* p = (char*)d_ws;
  auto alloc = [&](size_t bytes) {
    char* rp = p;
    p += (bytes + 255) & ~(size_t)255;
    return rp;
  };
  const size_t XB = (size_t)M_ * E_ * sizeof(bf16);        // 8 MiB
  const size_t WB = (size_t)E_ * E_ * sizeof(bf16);        // 2 MiB
  const size_t TB = (size_t)B_ * S_ * NT2 * sizeof(float); // 256 KiB
  bf16* Xh = (bf16*)alloc(XB);
  bf16* Xl = (bf16*)alloc(XB);
  bf16* WqTh = (bf16*)alloc(WB); bf16* WqTl = (bf16*)alloc(WB);
  bf16* WkTh = (bf16*)alloc(WB); bf16* WkTl = (bf16*)alloc(WB);
  bf16* WvTh = (bf16*)alloc(WB); bf16* WvTl = (bf16*)alloc(WB);
  bf16* WoTh = (bf16*)alloc(WB); bf16* WoTl = (bf16*)alloc(WB);
  float* cosT = (float*)alloc(TB);
  float* sinT = (float*)alloc(TB);
  bf16* Qh = (bf16*)alloc(XB); bf16* Qlo = (bf16*)alloc(XB);
  bf16* Kh = (bf16*)alloc(XB); bf16* Klo = (bf16*)alloc(XB);
  bf16* VTb = (bf16*)alloc(XB);
  // ctx aliases X (X is dead after the QKV GEMM; attn runs after on same stream)
  bf16* Ch = Xh;
  bf16* Cl = Xl;

  split_f32_kernel<<<M_ * E_ / 4 / 256, 256, 0, stream>>>(x, Xh, Xl, M_ * E_ / 4);
  dim3 tg(32, 32);
  transpose_split_kernel<<<tg, 256, 0, stream>>>(Wq, WqTh, WqTl);
  transpose_split_kernel<<<tg, 256, 0, stream>>>(Wk, WkTh, WkTl);
  transpose_split_kernel<<<tg, 256, 0, stream>>>(Wv, WvTh, WvTl);
  transpose_split_kernel<<<tg, 256, 0, stream>>>(Wo, WoTh, WoTl);
  rope_tab_kernel<<<B_ * S_ * NT2 / 256, 256, 0, stream>>>(pos, cosT, sinT);

  gemm_qkv_kernel<<<192, 512, 0, stream>>>(Xh, Xl, WqTh, WqTl, WkTh, WkTl, WvTh,
                                           WvTl, bq, bk, bv, cosT, sinT, Qh, Qlo,
                                           Kh, Klo, VTb);

  attn_kernel<<<B_ * H_ * (S_ / 128), 256, 0, stream>>>(Qh, Qlo, Kh, Klo, VTb,
                                                        Ch, Cl);

  gemm_o_kernel<<<256, 256, 0, stream>>>(Ch, Cl, WoTh, WoTl, bo, out);
}